// Round 13
// baseline (413.760 us; speedup 1.0000x reference)
//
#include <hip/hip_runtime.h>
#include <math.h>

// Channel attention (XCA-style). Round 13: R10 structure + G=2 (L3-resident
// intermediates) + m-fast GEMM grids (L2 panel reuse).
// b=8, c=256, H=W=128, heads=8, d=32, ps=4 -> nh=nw=32, e=16.
// Per group of G=2 batches:
//   conv_xt : x fp32 [b][c][p] -> xT bf16 [b*p][256]
//   K1 gemm<bf16out>: qkv = Wqkv_b @ xT^T -> bf16 [b][768][16384]
//   K2 dwconv_win: depthwise 3x3 -> bf16 dww[b][win][768][16]
//   K3 attn2: l2norm + 32x32 channel attn + PV -> attnT bf16 [b*p][256]
//   K4 gemm<f32out>: out = Wproj_b @ attnT^T -> fp32 [b][256][16384]

#define HW_ (128*128)
#define CHW_ (256*128*128)

typedef __attribute__((ext_vector_type(8))) short short8;
typedef __attribute__((ext_vector_type(4))) float f32x4;
typedef __attribute__((ext_vector_type(2))) _Float16 half2v;

static __device__ __forceinline__ unsigned short f2bf(float f) {
    unsigned int u = __float_as_uint(f);
    unsigned int r = (u + 0x7fffu + ((u >> 16) & 1u)) >> 16;   // RNE
    return (unsigned short)r;
}
static __device__ __forceinline__ float bf2f(unsigned short u) {
    return __uint_as_float(((unsigned int)u) << 16);
}
static __device__ __forceinline__ half2v pk16(float a, float b) {
    return __builtin_bit_cast(half2v, __builtin_amdgcn_cvt_pkrtz(a, b));
}

// ---- weights fp32 -> bf16 (768*256 + 256*256 = 262144 elems) ----
__global__ __launch_bounds__(256) void conv_w(
    const float* __restrict__ Wq, const float* __restrict__ Wp,
    unsigned short* __restrict__ out)
{
    int i = blockIdx.x * 256 + threadIdx.x;
    float v = (i < 196608) ? Wq[i] : Wp[i - 196608];
    out[i] = f2bf(v);
}

// ---- x [b][256][16384] fp32 -> xT [b*16384][256] bf16 ----
__global__ __launch_bounds__(256) void conv_xt(
    const float* __restrict__ xs, unsigned short* __restrict__ xT)
{
    __shared__ float tile[64][65];
    const int t = threadIdx.x;
    const int p0 = blockIdx.x * 64, c0 = blockIdx.y * 64;
    const float* xb = xs + (size_t)blockIdx.z * CHW_;
    unsigned short* xTb = xT + (size_t)blockIdx.z * HW_ * 256;
    {
        const int cl = t >> 4, pl = (t & 15) * 4;
        #pragma unroll
        for (int i = 0; i < 4; ++i) {
            float4 v = *reinterpret_cast<const float4*>(
                xb + (size_t)(c0 + cl + i * 16) * HW_ + p0 + pl);
            tile[cl + i * 16][pl + 0] = v.x;
            tile[cl + i * 16][pl + 1] = v.y;
            tile[cl + i * 16][pl + 2] = v.z;
            tile[cl + i * 16][pl + 3] = v.w;
        }
    }
    __syncthreads();
    #pragma unroll
    for (int i = 0; i < 2; ++i) {
        int chunk = i * 256 + t;
        int pr = chunk >> 3, c8 = (chunk & 7) * 8;
        short8 o;
        #pragma unroll
        for (int j = 0; j < 8; ++j)
            o[j] = (short)f2bf(tile[c8 + j][pr]);
        *reinterpret_cast<short8*>(xTb + (size_t)(p0 + pr) * 256 + c0 + c8) = o;
    }
}

// ---- bf16 MFMA GEMM: C[b][m][n] = sum_k A[m][k] * Bt[b*16384+n][k], K=256 --
// m-tiles on blockIdx.x (fast): consecutive blocks share the B n-panel (L2).
template<int BF16OUT>
__global__ __launch_bounds__(256) void gemm_bf16(
    const unsigned short* __restrict__ A,   // [M][256] bf16
    const unsigned short* __restrict__ Bt,  // [N][256] bf16
    void* __restrict__ Cv,                  // [G][M][16384]
    size_t strideBatch)
{
    __shared__ __align__(16) char smem[BF16OUT ? 16896 : 16384];

    const int t = threadIdx.x;
    const int lane = t & 63, wid = t >> 6;
    const int m0 = blockIdx.x * 128;
    const int n0 = blockIdx.y * 128;
    const int nb = n0 >> 14, nloc0 = n0 & 16383;
    const int wr = wid >> 1, wc = wid & 1;
    const int l15 = lane & 15, l4 = lane >> 4;

    const unsigned short* srcA[2];
    const unsigned short* srcB[2];
    #pragma unroll
    for (int i = 0; i < 2; ++i) {
        int u = i * 256 + t;
        int r = u >> 2, cs = u & 3;
        int c = cs ^ ((r ^ (r >> 2)) & 3);
        srcA[i] = A  + (size_t)(m0 + r) * 256 + c * 8;
        srcB[i] = Bt + (size_t)(n0 + r) * 256 + c * 8;
    }

    int ar[4], br[4];
    #pragma unroll
    for (int i = 0; i < 4; ++i) {
        int rm = wr * 64 + i * 16 + l15;
        ar[i] = rm * 4 + (l4 ^ ((rm ^ (rm >> 2)) & 3));
        int rn = wc * 64 + i * 16 + l15;
        br[i] = rn * 4 + (l4 ^ ((rn ^ (rn >> 2)) & 3));
    }

    f32x4 acc[4][4];
    #pragma unroll
    for (int i = 0; i < 4; ++i)
        #pragma unroll
        for (int j = 0; j < 4; ++j)
            acc[i][j] = (f32x4){0.f, 0.f, 0.f, 0.f};

    const short8* Ab = (const short8*)smem;
    const short8* Bb = (const short8*)(smem + 8192);

    for (int k0 = 0; k0 < 256; k0 += 32) {
        __syncthreads();
        #pragma unroll
        for (int i = 0; i < 2; ++i) {
            __builtin_amdgcn_global_load_lds(
                (const __attribute__((address_space(1))) void*)(srcA[i] + k0),
                (__attribute__((address_space(3))) void*)(smem + i * 4096 + wid * 1024),
                16, 0, 0);
            __builtin_amdgcn_global_load_lds(
                (const __attribute__((address_space(1))) void*)(srcB[i] + k0),
                (__attribute__((address_space(3))) void*)(smem + 8192 + i * 4096 + wid * 1024),
                16, 0, 0);
        }
        __syncthreads();
        short8 af[4], bf[4];
        #pragma unroll
        for (int i = 0; i < 4; ++i) { af[i] = Ab[ar[i]]; bf[i] = Bb[br[i]]; }
        #pragma unroll
        for (int am = 0; am < 4; ++am)
            #pragma unroll
            for (int bn = 0; bn < 4; ++bn)
                acc[am][bn] = __builtin_amdgcn_mfma_f32_16x16x32_bf16(
                    af[am], bf[bn], acc[am][bn], 0, 0, 0);
    }

    // C/D frag layout: col = lane&15, row = (lane>>4)*4 + reg
    if (BF16OUT) {
        unsigned short* Co = (unsigned short*)Cv + (size_t)nb * strideBatch + nloc0;
        float* ep = (float*)smem;          // [32][132]
        const int rr = t >> 3, c0 = (t & 7) * 16;
        #pragma unroll
        for (int am = 0; am < 4; ++am) {
            __syncthreads();
            #pragma unroll
            for (int q = 0; q < 4; ++q)
                #pragma unroll
                for (int bn = 0; bn < 4; ++bn)
                    ep[(wr * 16 + l4 * 4 + q) * 132 + wc * 64 + bn * 16 + l15] =
                        acc[am][bn][q];
            __syncthreads();
            short8 o0, o1;
            #pragma unroll
            for (int j = 0; j < 8; ++j) {
                o0[j] = (short)f2bf(ep[rr * 132 + c0 + j]);
                o1[j] = (short)f2bf(ep[rr * 132 + c0 + 8 + j]);
            }
            int m = m0 + (rr >> 4) * 64 + am * 16 + (rr & 15);
            unsigned short* p = Co + (size_t)m * 16384 + c0;
            *reinterpret_cast<short8*>(p) = o0;
            *reinterpret_cast<short8*>(p + 8) = o1;
        }
    } else {
        float* Co = (float*)Cv + (size_t)nb * strideBatch + nloc0;
        #pragma unroll
        for (int am = 0; am < 4; ++am)
            #pragma unroll
            for (int q = 0; q < 4; ++q) {
                int m = m0 + wr * 64 + am * 16 + l4 * 4 + q;
                #pragma unroll
                for (int bn = 0; bn < 4; ++bn)
                    Co[(size_t)m * 16384 + wc * 64 + bn * 16 + l15] =
                        acc[am][bn][q];
            }
    }
}

// ---- depthwise 3x3 (SAME, zero pad), bf16 in -> bf16 windowed out ----
__global__ __launch_bounds__(256) void dwconv_win(
    const unsigned short* __restrict__ qkv,  // [G][768][16384] bf16
    const float* __restrict__ Wdw,           // [768][9]
    unsigned short* __restrict__ dww)        // [G][1024][768][16] bf16
{
    const int t    = threadIdx.x;
    const int lane = t & 63;
    const int iw   = t & 31;
    const int chl  = t >> 5;
    const int wyl  = blockIdx.x;
    const int ch   = blockIdx.y * 8 + chl;
    const int bz   = blockIdx.z;

    float w[9];
    #pragma unroll
    for (int i = 0; i < 9; ++i) w[i] = Wdw[ch * 9 + i];

    float h[6][6];
    const unsigned short* plane = qkv + (size_t)(bz * 768 + ch) * HW_;
    #pragma unroll
    for (int r = 0; r < 6; ++r) {
        int gy = wyl * 4 - 1 + r;
        float c0 = 0.f, c1 = 0.f, c2 = 0.f, c3 = 0.f;
        if (gy >= 0 && gy < 128) {
            ushort4 u = *reinterpret_cast<const ushort4*>(
                plane + (size_t)gy * 128 + iw * 4);
            c0 = bf2f(u.x); c1 = bf2f(u.y); c2 = bf2f(u.z); c3 = bf2f(u.w);
        }
        float lf = __shfl(c3, (lane + 63) & 63);
        float rt = __shfl(c0, (lane + 1) & 63);
        h[r][0] = (iw == 0)  ? 0.f : lf;
        h[r][1] = c0; h[r][2] = c1; h[r][3] = c2; h[r][4] = c3;
        h[r][5] = (iw == 31) ? 0.f : rt;
    }

    unsigned short* outp =
        dww + ((size_t)(bz * 1024 + wyl * 32 + iw) * 768 + ch) * 16;
    short8 o0, o1;
    #pragma unroll
    for (int py = 0; py < 4; ++py) {
        #pragma unroll
        for (int px = 0; px < 4; ++px) {
            float s = 0.f;
            #pragma unroll
            for (int dy = 0; dy < 3; ++dy)
                #pragma unroll
                for (int dx = 0; dx < 3; ++dx)
                    s += h[py + dy][px + dx] * w[dy * 3 + dx];
            int e = py * 4 + px;
            if (e < 8) o0[e] = (short)f2bf(s); else o1[e - 8] = (short)f2bf(s);
        }
    }
    *reinterpret_cast<short8*>(outp) = o0;
    *reinterpret_cast<short8*>(outp + 8) = o1;
}

// ---- per-window channel attention (dot2-f16 QK, f32 PV) ----
__global__ __launch_bounds__(256) void attn2(
    const unsigned short* __restrict__ dww,  // [G][1024][768][16] bf16
    const float* __restrict__ temp,          // [8]
    unsigned short* __restrict__ attnT)      // [G*16384][256]
{
    __shared__ __align__(16) unsigned short ks[256 * 40]; // f16 rows, 80B stride
    __shared__ __align__(16) float vs[256 * 20];          // f32 rows, 80B stride
    const int t   = threadIdx.x;
    const int iw  = blockIdx.x;
    const int wyl = blockIdx.y;
    const int bz  = blockIdx.z;
    const int win = bz * 1024 + wyl * 32 + iw;
    const unsigned short* src = dww + (size_t)win * 12288;

    short8 a0 = *reinterpret_cast<const short8*>(src + t * 16);
    short8 a1 = *reinterpret_cast<const short8*>(src + t * 16 + 8);
    short8 b0 = *reinterpret_cast<const short8*>(src + (256 + t) * 16);
    short8 b1 = *reinterpret_cast<const short8*>(src + (256 + t) * 16 + 8);
    short8 c0 = *reinterpret_cast<const short8*>(src + (512 + t) * 16);
    short8 c1 = *reinterpret_cast<const short8*>(src + (512 + t) * 16 + 8);

    float q[16], kr[16], vr[16];
    #pragma unroll
    for (int j = 0; j < 8; ++j) {
        q[j]      = bf2f((unsigned short)a0[j]);
        q[8 + j]  = bf2f((unsigned short)a1[j]);
        kr[j]     = bf2f((unsigned short)b0[j]);
        kr[8 + j] = bf2f((unsigned short)b1[j]);
        vr[j]     = bf2f((unsigned short)c0[j]);
        vr[8 + j] = bf2f((unsigned short)c1[j]);
    }

    {
        float sq = 0.f, sk = 0.f;
        #pragma unroll
        for (int e = 0; e < 16; ++e) { sq += q[e] * q[e]; sk += kr[e] * kr[e]; }
        float cq = 1.0f / fmaxf(sqrtf(sq), 1e-12f);
        float ck = 1.0f / fmaxf(sqrtf(sk), 1e-12f);
        #pragma unroll
        for (int e = 0; e < 16; ++e) { q[e] *= cq; kr[e] *= ck; }
    }

    half2v q2[8], k2[8];
    #pragma unroll
    for (int j = 0; j < 8; ++j) {
        q2[j] = pk16(q[2 * j], q[2 * j + 1]);
        k2[j] = pk16(kr[2 * j], kr[2 * j + 1]);
    }

    *reinterpret_cast<short8*>(&ks[t * 40])     = *reinterpret_cast<short8*>(&k2[0]);
    *reinterpret_cast<short8*>(&ks[t * 40 + 8]) = *reinterpret_cast<short8*>(&k2[4]);
    {
        float* vp = &vs[t * 20];
        #pragma unroll
        for (int j = 0; j < 4; ++j)
            *reinterpret_cast<float4*>(vp + j * 4) =
                make_float4(vr[j*4], vr[j*4+1], vr[j*4+2], vr[j*4+3]);
    }
    __syncthreads();

    const int head = t >> 5;
    const float tmpv = temp[head];
    const unsigned short* kb = &ks[(head * 32) * 40];
    const float* vb = &vs[(head * 32) * 20];

    float lg[32];
    float mx = -1e30f;
    #pragma unroll
    for (int f = 0; f < 32; ++f) {
        short8 k0 = *reinterpret_cast<const short8*>(kb + f * 40);
        short8 k1 = *reinterpret_cast<const short8*>(kb + f * 40 + 8);
        half2v h0[4], h1[4];
        #pragma unroll
        for (int j = 0; j < 4; ++j) {
            h0[j] = __builtin_bit_cast(half2v, (int)(((int)(unsigned short)k0[2*j]) | (((int)(unsigned short)k0[2*j+1]) << 16)));
            h1[j] = __builtin_bit_cast(half2v, (int)(((int)(unsigned short)k1[2*j]) | (((int)(unsigned short)k1[2*j+1]) << 16)));
        }
        float s = 0.f;
        #pragma unroll
        for (int j = 0; j < 4; ++j) s = __builtin_amdgcn_fdot2(q2[j], h0[j], s, false);
        #pragma unroll
        for (int j = 0; j < 4; ++j) s = __builtin_amdgcn_fdot2(q2[4 + j], h1[j], s, false);
        s *= tmpv;
        lg[f] = s;
        mx = fmaxf(mx, s);
    }
    float sum = 0.f;
    #pragma unroll
    for (int f = 0; f < 32; ++f) { lg[f] = __expf(lg[f] - mx); sum += lg[f]; }
    const float inv = 1.0f / sum;

    float o[16];
    #pragma unroll
    for (int e = 0; e < 16; ++e) o[e] = 0.f;
    #pragma unroll
    for (int f = 0; f < 32; ++f) {
        float p = lg[f];
        #pragma unroll
        for (int j = 0; j < 4; ++j) {
            float4 v4 = *reinterpret_cast<const float4*>(vb + f * 20 + j * 4);
            o[j*4]   += p * v4.x; o[j*4+1] += p * v4.y;
            o[j*4+2] += p * v4.z; o[j*4+3] += p * v4.w;
        }
    }

    #pragma unroll
    for (int e = 0; e < 16; ++e) {
        int py = e >> 2, px = e & 3;
        size_t pl = (size_t)bz * HW_ + (wyl * 4 + py) * 128 + iw * 4 + px;
        attnT[pl * 256 + t] = f2bf(o[e] * inv);
    }
}

extern "C" void kernel_launch(void* const* d_in, const int* in_sizes, int n_in,
                              void* d_out, int out_size, void* d_ws, size_t ws_size,
                              hipStream_t stream) {
    const float* x     = (const float*)d_in[0];
    const float* Wqkv  = (const float*)d_in[1];
    const float* Wdw   = (const float*)d_in[2];
    const float* temp  = (const float*)d_in[3];
    const float* Wproj = (const float*)d_in[4];
    float* out = (float*)d_out;

    unsigned short* Wb = (unsigned short*)d_ws;        // 262144 bf16
    const size_t offW = 262144 * 2;

    // per-batch buffer bytes
    const size_t xtB  = (size_t)HW_ * 256 * 2;         // 8 MiB
    const size_t qkvB = (size_t)768 * HW_ * 2;         // 24 MiB
    const size_t dwwB = (size_t)1024 * 768 * 16 * 2;   // 24 MiB
    const size_t atB  = (size_t)HW_ * 256 * 2;         // 8 MiB
    const size_t perB = xtB + qkvB + dwwB + atB;       // 64 MiB

    // G=2: per-group intermediates (176 MiB incl. x reads) fit the 256 MiB
    // Infinity Cache -> producer->consumer handoffs stay L3-resident.
    int G = 2;
    while (G > 1 && offW + (size_t)G * perB > ws_size) G >>= 1;

    unsigned short* xT    = (unsigned short*)((char*)d_ws + offW);
    unsigned short* qkv   = (unsigned short*)((char*)d_ws + offW + (size_t)G * xtB);
    unsigned short* dww   = (unsigned short*)((char*)d_ws + offW + (size_t)G * (xtB + qkvB));
    unsigned short* attnT = (unsigned short*)((char*)d_ws + offW + (size_t)G * (xtB + qkvB + dwwB));

    conv_w<<<1024, 256, 0, stream>>>(Wqkv, Wproj, Wb);

    for (int b0 = 0; b0 < 8; b0 += G) {
        conv_xt<<<dim3(HW_ / 64, 4, G), 256, 0, stream>>>(
            x + (size_t)b0 * CHW_, xT);

        // K1: m-fast (6 m-tiles share each xT n-panel in L2)
        gemm_bf16<1><<<dim3(6, G * 128), 256, 0, stream>>>(
            Wb, xT, qkv, (size_t)768 * HW_);

        dwconv_win<<<dim3(32, 96, G), 256, 0, stream>>>(
            qkv, Wdw, dww);

        attn2<<<dim3(32, 32, G), 256, 0, stream>>>(
            dww, temp, attnT);

        // K4: m-fast
        gemm_bf16<0><<<dim3(2, G * 128), 256, 0, stream>>>(
            Wb + 196608, attnT, out + (size_t)b0 * CHW_, (size_t)CHW_);
    }
}

// Round 14
// 382.735 us; speedup vs baseline: 1.0811x; 1.0811x over previous
//
#include <hip/hip_runtime.h>
#include <math.h>

// Channel attention (XCA-style). Round 14: restore R10 champion (383 us).
// b=8, c=256, H=W=128, heads=8, d=32, ps=4 -> nh=nw=32, e=16.
// Single pass (G=8):
//   conv_xt : x fp32 [b][c][p] -> xT bf16 [b*p][256]
//   K1 gemm<bf16out>: qkv = Wqkv_b @ xT^T -> bf16 [b][768][16384]
//   K2 dwconv_win: depthwise 3x3 -> bf16 dww[b][win][768][16]
//   K3 attn2: l2norm + 32x32 channel attn + PV -> attnT bf16 [b*p][256]
//   K4 gemm<f32out>: out = Wproj_b @ attnT^T -> fp32 [b][256][16384]

#define HW_ (128*128)
#define CHW_ (256*128*128)

typedef __attribute__((ext_vector_type(8))) short short8;
typedef __attribute__((ext_vector_type(4))) float f32x4;
typedef __attribute__((ext_vector_type(2))) _Float16 half2v;

static __device__ __forceinline__ unsigned short f2bf(float f) {
    unsigned int u = __float_as_uint(f);
    unsigned int r = (u + 0x7fffu + ((u >> 16) & 1u)) >> 16;   // RNE
    return (unsigned short)r;
}
static __device__ __forceinline__ float bf2f(unsigned short u) {
    return __uint_as_float(((unsigned int)u) << 16);
}
static __device__ __forceinline__ half2v pk16(float a, float b) {
    return __builtin_bit_cast(half2v, __builtin_amdgcn_cvt_pkrtz(a, b));
}

// ---- weights fp32 -> bf16 (768*256 + 256*256 = 262144 elems) ----
__global__ __launch_bounds__(256) void conv_w(
    const float* __restrict__ Wq, const float* __restrict__ Wp,
    unsigned short* __restrict__ out)
{
    int i = blockIdx.x * 256 + threadIdx.x;
    float v = (i < 196608) ? Wq[i] : Wp[i - 196608];
    out[i] = f2bf(v);
}

// ---- x [b][256][16384] fp32 -> xT [b*16384][256] bf16 ----
__global__ __launch_bounds__(256) void conv_xt(
    const float* __restrict__ xs, unsigned short* __restrict__ xT)
{
    __shared__ float tile[64][65];
    const int t = threadIdx.x;
    const int p0 = blockIdx.x * 64, c0 = blockIdx.y * 64;
    const float* xb = xs + (size_t)blockIdx.z * CHW_;
    unsigned short* xTb = xT + (size_t)blockIdx.z * HW_ * 256;
    {
        const int cl = t >> 4, pl = (t & 15) * 4;
        #pragma unroll
        for (int i = 0; i < 4; ++i) {
            float4 v = *reinterpret_cast<const float4*>(
                xb + (size_t)(c0 + cl + i * 16) * HW_ + p0 + pl);
            tile[cl + i * 16][pl + 0] = v.x;
            tile[cl + i * 16][pl + 1] = v.y;
            tile[cl + i * 16][pl + 2] = v.z;
            tile[cl + i * 16][pl + 3] = v.w;
        }
    }
    __syncthreads();
    #pragma unroll
    for (int i = 0; i < 2; ++i) {
        int chunk = i * 256 + t;
        int pr = chunk >> 3, c8 = (chunk & 7) * 8;
        short8 o;
        #pragma unroll
        for (int j = 0; j < 8; ++j)
            o[j] = (short)f2bf(tile[c8 + j][pr]);
        *reinterpret_cast<short8*>(xTb + (size_t)(p0 + pr) * 256 + c0 + c8) = o;
    }
}

// ---- bf16 MFMA GEMM: C[b][m][n] = sum_k A[m][k] * Bt[b*16384+n][k], K=256 --
// 128x128 tile, 4 waves (2x2), 4x4 frags of 16x16x32, fp32 accum.
template<int BF16OUT>
__global__ __launch_bounds__(256) void gemm_bf16(
    const unsigned short* __restrict__ A,   // [M][256] bf16
    const unsigned short* __restrict__ Bt,  // [N][256] bf16
    void* __restrict__ Cv,                  // [G][M][16384]
    size_t strideBatch)
{
    __shared__ __align__(16) char smem[BF16OUT ? 16896 : 16384];

    const int t = threadIdx.x;
    const int lane = t & 63, wid = t >> 6;
    const int m0 = blockIdx.y * 128, n0 = blockIdx.x * 128;
    const int nb = n0 >> 14, nloc0 = n0 & 16383;
    const int wr = wid >> 1, wc = wid & 1;
    const int l15 = lane & 15, l4 = lane >> 4;

    const unsigned short* srcA[2];
    const unsigned short* srcB[2];
    #pragma unroll
    for (int i = 0; i < 2; ++i) {
        int u = i * 256 + t;
        int r = u >> 2, cs = u & 3;
        int c = cs ^ ((r ^ (r >> 2)) & 3);
        srcA[i] = A  + (size_t)(m0 + r) * 256 + c * 8;
        srcB[i] = Bt + (size_t)(n0 + r) * 256 + c * 8;
    }

    int ar[4], br[4];
    #pragma unroll
    for (int i = 0; i < 4; ++i) {
        int rm = wr * 64 + i * 16 + l15;
        ar[i] = rm * 4 + (l4 ^ ((rm ^ (rm >> 2)) & 3));
        int rn = wc * 64 + i * 16 + l15;
        br[i] = rn * 4 + (l4 ^ ((rn ^ (rn >> 2)) & 3));
    }

    f32x4 acc[4][4];
    #pragma unroll
    for (int i = 0; i < 4; ++i)
        #pragma unroll
        for (int j = 0; j < 4; ++j)
            acc[i][j] = (f32x4){0.f, 0.f, 0.f, 0.f};

    const short8* Ab = (const short8*)smem;
    const short8* Bb = (const short8*)(smem + 8192);

    for (int k0 = 0; k0 < 256; k0 += 32) {
        __syncthreads();
        #pragma unroll
        for (int i = 0; i < 2; ++i) {
            __builtin_amdgcn_global_load_lds(
                (const __attribute__((address_space(1))) void*)(srcA[i] + k0),
                (__attribute__((address_space(3))) void*)(smem + i * 4096 + wid * 1024),
                16, 0, 0);
            __builtin_amdgcn_global_load_lds(
                (const __attribute__((address_space(1))) void*)(srcB[i] + k0),
                (__attribute__((address_space(3))) void*)(smem + 8192 + i * 4096 + wid * 1024),
                16, 0, 0);
        }
        __syncthreads();
        short8 af[4], bf[4];
        #pragma unroll
        for (int i = 0; i < 4; ++i) { af[i] = Ab[ar[i]]; bf[i] = Bb[br[i]]; }
        #pragma unroll
        for (int am = 0; am < 4; ++am)
            #pragma unroll
            for (int bn = 0; bn < 4; ++bn)
                acc[am][bn] = __builtin_amdgcn_mfma_f32_16x16x32_bf16(
                    af[am], bf[bn], acc[am][bn], 0, 0, 0);
    }

    // C/D frag layout: col = lane&15, row = (lane>>4)*4 + reg
    if (BF16OUT) {
        unsigned short* Co = (unsigned short*)Cv + (size_t)nb * strideBatch + nloc0;
        float* ep = (float*)smem;          // [32][132]
        const int rr = t >> 3, c0 = (t & 7) * 16;
        #pragma unroll
        for (int am = 0; am < 4; ++am) {
            __syncthreads();
            #pragma unroll
            for (int q = 0; q < 4; ++q)
                #pragma unroll
                for (int bn = 0; bn < 4; ++bn)
                    ep[(wr * 16 + l4 * 4 + q) * 132 + wc * 64 + bn * 16 + l15] =
                        acc[am][bn][q];
            __syncthreads();
            short8 o0, o1;
            #pragma unroll
            for (int j = 0; j < 8; ++j) {
                o0[j] = (short)f2bf(ep[rr * 132 + c0 + j]);
                o1[j] = (short)f2bf(ep[rr * 132 + c0 + 8 + j]);
            }
            int m = m0 + (rr >> 4) * 64 + am * 16 + (rr & 15);
            unsigned short* p = Co + (size_t)m * 16384 + c0;
            *reinterpret_cast<short8*>(p) = o0;
            *reinterpret_cast<short8*>(p + 8) = o1;
        }
    } else {
        float* Co = (float*)Cv + (size_t)nb * strideBatch + nloc0;
        #pragma unroll
        for (int am = 0; am < 4; ++am)
            #pragma unroll
            for (int q = 0; q < 4; ++q) {
                int m = m0 + wr * 64 + am * 16 + l4 * 4 + q;
                #pragma unroll
                for (int bn = 0; bn < 4; ++bn)
                    Co[(size_t)m * 16384 + wc * 64 + bn * 16 + l15] =
                        acc[am][bn][q];
            }
    }
}

// ---- depthwise 3x3 (SAME, zero pad), bf16 in -> bf16 windowed out ----
__global__ __launch_bounds__(256) void dwconv_win(
    const unsigned short* __restrict__ qkv,  // [G][768][16384] bf16
    const float* __restrict__ Wdw,           // [768][9]
    unsigned short* __restrict__ dww)        // [G][1024][768][16] bf16
{
    const int t    = threadIdx.x;
    const int lane = t & 63;
    const int iw   = t & 31;
    const int chl  = t >> 5;
    const int wyl  = blockIdx.x;
    const int ch   = blockIdx.y * 8 + chl;
    const int bz   = blockIdx.z;

    float w[9];
    #pragma unroll
    for (int i = 0; i < 9; ++i) w[i] = Wdw[ch * 9 + i];

    float h[6][6];
    const unsigned short* plane = qkv + (size_t)(bz * 768 + ch) * HW_;
    #pragma unroll
    for (int r = 0; r < 6; ++r) {
        int gy = wyl * 4 - 1 + r;
        float c0 = 0.f, c1 = 0.f, c2 = 0.f, c3 = 0.f;
        if (gy >= 0 && gy < 128) {
            ushort4 u = *reinterpret_cast<const ushort4*>(
                plane + (size_t)gy * 128 + iw * 4);
            c0 = bf2f(u.x); c1 = bf2f(u.y); c2 = bf2f(u.z); c3 = bf2f(u.w);
        }
        float lf = __shfl(c3, (lane + 63) & 63);
        float rt = __shfl(c0, (lane + 1) & 63);
        h[r][0] = (iw == 0)  ? 0.f : lf;
        h[r][1] = c0; h[r][2] = c1; h[r][3] = c2; h[r][4] = c3;
        h[r][5] = (iw == 31) ? 0.f : rt;
    }

    unsigned short* outp =
        dww + ((size_t)(bz * 1024 + wyl * 32 + iw) * 768 + ch) * 16;
    short8 o0, o1;
    #pragma unroll
    for (int py = 0; py < 4; ++py) {
        #pragma unroll
        for (int px = 0; px < 4; ++px) {
            float s = 0.f;
            #pragma unroll
            for (int dy = 0; dy < 3; ++dy)
                #pragma unroll
                for (int dx = 0; dx < 3; ++dx)
                    s += h[py + dy][px + dx] * w[dy * 3 + dx];
            int e = py * 4 + px;
            if (e < 8) o0[e] = (short)f2bf(s); else o1[e - 8] = (short)f2bf(s);
        }
    }
    *reinterpret_cast<short8*>(outp) = o0;
    *reinterpret_cast<short8*>(outp + 8) = o1;
}

// ---- per-window channel attention (dot2-f16 QK, f32 PV) ----
__global__ __launch_bounds__(256) void attn2(
    const unsigned short* __restrict__ dww,  // [G][1024][768][16] bf16
    const float* __restrict__ temp,          // [8]
    unsigned short* __restrict__ attnT)      // [G*16384][256]
{
    __shared__ __align__(16) unsigned short ks[256 * 40]; // f16 rows, 80B stride
    __shared__ __align__(16) float vs[256 * 20];          // f32 rows, 80B stride
    const int t   = threadIdx.x;
    const int iw  = blockIdx.x;
    const int wyl = blockIdx.y;
    const int bz  = blockIdx.z;
    const int win = bz * 1024 + wyl * 32 + iw;
    const unsigned short* src = dww + (size_t)win * 12288;

    short8 a0 = *reinterpret_cast<const short8*>(src + t * 16);
    short8 a1 = *reinterpret_cast<const short8*>(src + t * 16 + 8);
    short8 b0 = *reinterpret_cast<const short8*>(src + (256 + t) * 16);
    short8 b1 = *reinterpret_cast<const short8*>(src + (256 + t) * 16 + 8);
    short8 c0 = *reinterpret_cast<const short8*>(src + (512 + t) * 16);
    short8 c1 = *reinterpret_cast<const short8*>(src + (512 + t) * 16 + 8);

    float q[16], kr[16], vr[16];
    #pragma unroll
    for (int j = 0; j < 8; ++j) {
        q[j]      = bf2f((unsigned short)a0[j]);
        q[8 + j]  = bf2f((unsigned short)a1[j]);
        kr[j]     = bf2f((unsigned short)b0[j]);
        kr[8 + j] = bf2f((unsigned short)b1[j]);
        vr[j]     = bf2f((unsigned short)c0[j]);
        vr[8 + j] = bf2f((unsigned short)c1[j]);
    }

    {
        float sq = 0.f, sk = 0.f;
        #pragma unroll
        for (int e = 0; e < 16; ++e) { sq += q[e] * q[e]; sk += kr[e] * kr[e]; }
        float cq = 1.0f / fmaxf(sqrtf(sq), 1e-12f);
        float ck = 1.0f / fmaxf(sqrtf(sk), 1e-12f);
        #pragma unroll
        for (int e = 0; e < 16; ++e) { q[e] *= cq; kr[e] *= ck; }
    }

    half2v q2[8], k2[8];
    #pragma unroll
    for (int j = 0; j < 8; ++j) {
        q2[j] = pk16(q[2 * j], q[2 * j + 1]);
        k2[j] = pk16(kr[2 * j], kr[2 * j + 1]);
    }

    *reinterpret_cast<short8*>(&ks[t * 40])     = *reinterpret_cast<short8*>(&k2[0]);
    *reinterpret_cast<short8*>(&ks[t * 40 + 8]) = *reinterpret_cast<short8*>(&k2[4]);
    {
        float* vp = &vs[t * 20];
        #pragma unroll
        for (int j = 0; j < 4; ++j)
            *reinterpret_cast<float4*>(vp + j * 4) =
                make_float4(vr[j*4], vr[j*4+1], vr[j*4+2], vr[j*4+3]);
    }
    __syncthreads();

    const int head = t >> 5;
    const float tmpv = temp[head];
    const unsigned short* kb = &ks[(head * 32) * 40];
    const float* vb = &vs[(head * 32) * 20];

    float lg[32];
    float mx = -1e30f;
    #pragma unroll
    for (int f = 0; f < 32; ++f) {
        short8 k0 = *reinterpret_cast<const short8*>(kb + f * 40);
        short8 k1 = *reinterpret_cast<const short8*>(kb + f * 40 + 8);
        half2v h0[4], h1[4];
        #pragma unroll
        for (int j = 0; j < 4; ++j) {
            h0[j] = __builtin_bit_cast(half2v, (int)(((int)(unsigned short)k0[2*j]) | (((int)(unsigned short)k0[2*j+1]) << 16)));
            h1[j] = __builtin_bit_cast(half2v, (int)(((int)(unsigned short)k1[2*j]) | (((int)(unsigned short)k1[2*j+1]) << 16)));
        }
        float s = 0.f;
        #pragma unroll
        for (int j = 0; j < 4; ++j) s = __builtin_amdgcn_fdot2(q2[j], h0[j], s, false);
        #pragma unroll
        for (int j = 0; j < 4; ++j) s = __builtin_amdgcn_fdot2(q2[4 + j], h1[j], s, false);
        s *= tmpv;
        lg[f] = s;
        mx = fmaxf(mx, s);
    }
    float sum = 0.f;
    #pragma unroll
    for (int f = 0; f < 32; ++f) { lg[f] = __expf(lg[f] - mx); sum += lg[f]; }
    const float inv = 1.0f / sum;

    float o[16];
    #pragma unroll
    for (int e = 0; e < 16; ++e) o[e] = 0.f;
    #pragma unroll
    for (int f = 0; f < 32; ++f) {
        float p = lg[f];
        #pragma unroll
        for (int j = 0; j < 4; ++j) {
            float4 v4 = *reinterpret_cast<const float4*>(vb + f * 20 + j * 4);
            o[j*4]   += p * v4.x; o[j*4+1] += p * v4.y;
            o[j*4+2] += p * v4.z; o[j*4+3] += p * v4.w;
        }
    }

    #pragma unroll
    for (int e = 0; e < 16; ++e) {
        int py = e >> 2, px = e & 3;
        size_t pl = (size_t)bz * HW_ + (wyl * 4 + py) * 128 + iw * 4 + px;
        attnT[pl * 256 + t] = f2bf(o[e] * inv);
    }
}

extern "C" void kernel_launch(void* const* d_in, const int* in_sizes, int n_in,
                              void* d_out, int out_size, void* d_ws, size_t ws_size,
                              hipStream_t stream) {
    const float* x     = (const float*)d_in[0];
    const float* Wqkv  = (const float*)d_in[1];
    const float* Wdw   = (const float*)d_in[2];
    const float* temp  = (const float*)d_in[3];
    const float* Wproj = (const float*)d_in[4];
    float* out = (float*)d_out;

    unsigned short* Wb = (unsigned short*)d_ws;        // 262144 bf16
    const size_t offW = 262144 * 2;

    // per-batch buffer bytes
    const size_t xtB  = (size_t)HW_ * 256 * 2;         // 8 MiB
    const size_t qkvB = (size_t)768 * HW_ * 2;         // 24 MiB
    const size_t dwwB = (size_t)1024 * 768 * 16 * 2;   // 24 MiB
    const size_t atB  = (size_t)HW_ * 256 * 2;         // 8 MiB
    const size_t perB = xtB + qkvB + dwwB + atB;       // 64 MiB

    int G = 8;
    while (G > 1 && offW + (size_t)G * perB > ws_size) G >>= 1;

    unsigned short* xT    = (unsigned short*)((char*)d_ws + offW);
    unsigned short* qkv   = (unsigned short*)((char*)d_ws + offW + (size_t)G * xtB);
    unsigned short* dww   = (unsigned short*)((char*)d_ws + offW + (size_t)G * (xtB + qkvB));
    unsigned short* attnT = (unsigned short*)((char*)d_ws + offW + (size_t)G * (xtB + qkvB + dwwB));

    conv_w<<<1024, 256, 0, stream>>>(Wqkv, Wproj, Wb);

    for (int b0 = 0; b0 < 8; b0 += G) {
        conv_xt<<<dim3(HW_ / 64, 4, G), 256, 0, stream>>>(
            x + (size_t)b0 * CHW_, xT);

        gemm_bf16<1><<<dim3(G * 128, 6), 256, 0, stream>>>(
            Wb, xT, qkv, (size_t)768 * HW_);

        dwconv_win<<<dim3(32, 96, G), 256, 0, stream>>>(
            qkv, Wdw, dww);

        attn2<<<dim3(32, 32, G), 256, 0, stream>>>(
            dww, temp, attnT);

        gemm_bf16<0><<<dim3(G * 128, 2), 256, 0, stream>>>(
            Wb + 196608, attnT, out + (size_t)b0 * CHW_, (size_t)CHW_);
    }
}